// Round 7
// baseline (58.996 us; speedup 1.0000x reference)
//
#include <hip/hip_runtime.h>

#define UNITS 256
#define BATCH 256
#define NBLK  2048

typedef float fx4 __attribute__((ext_vector_type(4)));

// 2-barrier inclusive scan of segment sizes -> s_ends[256]
__device__ __forceinline__ void scan_sizes(const int* __restrict__ nclasses,
                                           const int* __restrict__ nfeature,
                                           int* s_ends, int* s_wsum,
                                           int t, int ln, int rl) {
    int v = nclasses[t] * nfeature[t];
    #pragma unroll
    for (int off = 1; off < 64; off <<= 1) {
        int u = __shfl_up(v, off, 64);
        if (ln >= off) v += u;
    }
    if (ln == 63) s_wsum[rl] = v;
    __syncthreads();
    int base = 0;
    #pragma unroll
    for (int w = 0; w < 3; ++w)
        if (w < rl) base += s_wsum[w];
    s_ends[t] = v + base;
    __syncthreads();
}

// Phase 1: per-block partial sums, TAGGED by segment id (divergence-proof).
// R5 geometry (proven fastest): wave rl reads rows r0+rl, +4, ... (one
// interleaved front per block); lane owns a float4 column slice. 3 static
// unrolled runs (chunk <=136 rows, min segment 100 -> <=3 segments/block,
// <=2 boundaries/wave). Each run's partial is tagged with the wave's own seg
// id; the merge assigns by tag, so per-wave cursor divergence at chunk start
// is harmless (the R5 structure had a latent race here). No atomics: merged
// 3-slot partials + seg0 go to d_ws; ONE barrier per block.
__global__ __launch_bounds__(256, 8) void k_part(const float* __restrict__ x,
                                                 const int* __restrict__ nclasses,
                                                 const int* __restrict__ nfeature,
                                                 float* __restrict__ part,
                                                 int* __restrict__ pseg,
                                                 int total_rows, int lo, int nE4) {
    __shared__ int   s_ends[BATCH];
    __shared__ int   s_wsum[4];
    __shared__ int   s_seg[4][3];
    __shared__ float s_red[4][3][256];
    const int t = threadIdx.x, ln = t & 63, rl = t >> 6;
    scan_sizes(nclasses, nfeature, s_ends, s_wsum, t, ln, rl);

    const int b    = blockIdx.x;
    const int hi   = lo + 4;
    const int r0   = (b < nE4) ? b * hi : nE4 * hi + (b - nE4) * lo;
    const int csz  = (b < nE4) ? hi : lo;
    const int rend = min(r0 + csz, total_rows);
    if (r0 >= rend) {                       // only for tiny inputs
        #pragma unroll
        for (int d = 0; d < 3; ++d) part[(b * 3 + d) * 256 + t] = 0.f;
        if (t == 0) pseg[b] = 0;
        return;
    }

    int r = r0 + rl;                        // per-wave row cursor
    const int key = min(r, rend - 1);
    int bl = 0, bh = BATCH;                 // first segment with end > key
    while (bl < bh) {
        int mid = (bl + bh) >> 1;
        if (s_ends[mid] > key) bh = mid; else bl = mid + 1;
    }
    int seg = bl;

    const float* p = x + (size_t)r * UNITS + (ln << 2);

    #pragma unroll
    for (int run = 0; run < 3; ++run) {
        const int stop = min(s_ends[seg], rend);
        int cnt = (stop - r + 3) >> 2;      // this wave's rows in [r, stop)
        if (cnt < 0) cnt = 0;
        r += cnt << 2;

        fx4 acc = {0.f, 0.f, 0.f, 0.f};
        int k = 0;
        for (; k + 4 <= cnt; k += 4) {      // 4 outstanding 16B loads/lane
            fx4 v0 = *(const fx4*)(p);
            fx4 v1 = *(const fx4*)(p + 4  * UNITS);
            fx4 v2 = *(const fx4*)(p + 8  * UNITS);
            fx4 v3 = *(const fx4*)(p + 12 * UNITS);
            p += 16 * UNITS;
            acc += (v0 + v1) + (v2 + v3);
        }
        for (; k < cnt; ++k) {
            fx4 v = *(const fx4*)(p);
            p += 4 * UNITS;
            acc += v;
        }

        if (ln == 0) s_seg[rl][run] = seg;  // tag with THIS wave's segment
        *reinterpret_cast<fx4*>(&s_red[rl][run][ln << 2]) = acc;
        if (s_ends[seg] <= r && r < rend) ++seg;  // next segment ( >=100 apart )
    }
    __syncthreads();

    // tagged 3-slot merge: slot d = tag - seg0 (seg0 = wave0/run0 = block min)
    const int seg0 = s_seg[0][0];
    float a0 = 0.f, a1 = 0.f, a2 = 0.f;
    #pragma unroll
    for (int w = 0; w < 4; ++w) {
        #pragma unroll
        for (int run = 0; run < 3; ++run) {
            const int d = s_seg[w][run] - seg0;
            const float v = s_red[w][run][t];
            a0 += (d == 0) ? v : 0.f;
            a1 += (d == 1) ? v : 0.f;
            a2 += (d == 2) ? v : 0.f;
        }
    }
    part[(b * 3 + 0) * 256 + t] = a0;
    part[(b * 3 + 1) * 256 + t] = a1;
    part[(b * 3 + 2) * 256 + t] = a2;
    if (t == 0) pseg[b] = seg0;
}

// Phase 2: block i gathers segment i's partials from the <=24 covering blocks
// (chunk geometry is invertible), scales by 1/size, plain store (no zeroing
// kernel needed, out fully overwritten).
__global__ __launch_bounds__(256, 8) void k_final(const float* __restrict__ part,
                                                  const int* __restrict__ pseg,
                                                  const int* __restrict__ nclasses,
                                                  const int* __restrict__ nfeature,
                                                  float* __restrict__ out,
                                                  int total_rows, int lo, int nE4) {
    __shared__ int s_ends[BATCH];
    __shared__ int s_wsum[4];
    const int t = threadIdx.x, ln = t & 63, rl = t >> 6;
    scan_sizes(nclasses, nfeature, s_ends, s_wsum, t, ln, rl);

    const int i     = blockIdx.x;
    const int start = (i == 0) ? 0 : s_ends[i - 1];
    const int end   = s_ends[i];
    const int hi    = lo + 4;
    const int tierA = nE4 * hi;

    const int Rl = start, Rr = end - 1;     // first/last row of segment i
    int b_first = (Rl < tierA) ? (Rl / hi)
                               : (lo ? nE4 + (Rl - tierA) / lo : NBLK - 1);
    int b_last  = (Rr < tierA) ? (Rr / hi)
                               : (lo ? nE4 + (Rr - tierA) / lo : NBLK - 1);
    if (b_last >= NBLK) b_last = NBLK - 1;

    float sum = 0.f;
    for (int b = b_first; b <= b_last; ++b) {
        const int d = i - pseg[b];
        if (0 <= d && d <= 2) sum += part[(b * 3 + d) * 256 + t];
    }
    const float inv = 1.0f / (float)(nclasses[i] * nfeature[i]);
    out[i * UNITS + t] = sum * inv;
}

extern "C" void kernel_launch(void* const* d_in, const int* in_sizes, int n_in,
                              void* d_out, int out_size, void* d_ws, size_t ws_size,
                              hipStream_t stream) {
    const float* x        = (const float*)d_in[0];
    const int*   nclasses = (const int*)d_in[1];
    const int*   nfeature = (const int*)d_in[2];
    float*       out      = (float*)d_out;
    float*       part     = (float*)d_ws;                       // 6.29 MB
    int*         pseg     = (int*)((char*)d_ws + NBLK * 3 * 256 * sizeof(float));

    const int total_rows = in_sizes[0] / UNITS;

    // balanced two-tier chunking over exactly 2048 blocks
    const int q   = total_rows >> 11;         // total/2048
    const int lo  = q & ~3;                   // lower chunk, multiple of 4
    const int E   = total_rows - (lo << 11);  // leftover rows
    const int nE4 = (E + 3) >> 2;             // blocks that take lo+4 rows

    k_part<<<NBLK, 256, 0, stream>>>(x, nclasses, nfeature, part, pseg,
                                     total_rows, lo, nE4);
    k_final<<<BATCH, 256, 0, stream>>>(part, pseg, nclasses, nfeature, out,
                                       total_rows, lo, nE4);
}

// Round 8
// 53.999 us; speedup vs baseline: 1.0925x; 1.0925x over previous
//
#include <hip/hip_runtime.h>

#define UNITS 256
#define BATCH 256

typedef float fx4 __attribute__((ext_vector_type(4)));

// Kernel 1: pure zeroing of out[256][256] (atomic flush target). 256KB.
__global__ __launch_bounds__(256) void k_zero(float* __restrict__ out) {
    const int i = (blockIdx.x * 256 + threadIdx.x) << 2;
    *reinterpret_cast<fx4*>(out + i) = fx4{0.f, 0.f, 0.f, 0.f};
}

// Kernel 2: chunked accumulation, block-uniform segment walk.
// Best-of-session structure (53.8us): interleaved per-wave row fronts,
// x4 unroll (4 outstanding 16B loads/lane; x8 crosses the 64-VGPR occupancy
// step and regressed), plain loads (nontemporal regressed), per-segment
// all-thread flush (256 parallel atomics, divide folded in).
// The walk is BLOCK-UNIFORM: binary search keys on r0 and the segment
// cursor advances uniformly, so flush points are synchronized and there is
// no per-wave cursor divergence (unlike the contiguous-per-wave variant).
__global__ __launch_bounds__(256) void k_accum(const float* __restrict__ x,
                                               const int* __restrict__ nclasses,
                                               const int* __restrict__ nfeature,
                                               float* __restrict__ out,
                                               int total_rows, int lo, int nE4) {
    __shared__ int   s_ends[BATCH];
    __shared__ float s_inv[BATCH];
    __shared__ int   s_wsum[4];
    __shared__ float s_red[4][64][4];
    const int t  = threadIdx.x;
    const int ln = t & 63;
    const int rl = t >> 6;

    // ---- 2-barrier inclusive scan of sizes -> s_ends ----
    {
        const int sz = nclasses[t] * nfeature[t];
        s_inv[t] = 1.0f / (float)sz;
        int v = sz;
        #pragma unroll
        for (int off = 1; off < 64; off <<= 1) {
            int u = __shfl_up(v, off, 64);
            if (ln >= off) v += u;
        }
        if (ln == 63) s_wsum[rl] = v;
        __syncthreads();
        int base = 0;
        #pragma unroll
        for (int w = 0; w < 3; ++w)
            if (w < rl) base += s_wsum[w];
        s_ends[t] = v + base;
        __syncthreads();
    }

    // ---- balanced chunk geometry (exactly 2048 blocks, no stragglers) ----
    const int b    = blockIdx.x;
    const int hi   = lo + 4;
    const int r0   = (b < nE4) ? b * hi : nE4 * hi + (b - nE4) * lo;
    const int csz  = (b < nE4) ? hi : lo;
    const int rend = min(r0 + csz, total_rows);
    if (r0 >= rend) return;               // block-uniform

    // block-uniform binary search: first segment with end > r0
    int slo = 0, shi = BATCH;
    while (slo < shi) {
        int mid = (slo + shi) >> 1;
        if (s_ends[mid] > r0) shi = mid; else slo = mid + 1;
    }
    int seg = slo;

    const int c = ln << 2;                // column start (0,4,...,252)
    int r = r0 + rl;                      // per-wave row cursor
    const float* p = x + (size_t)r * UNITS + c;
    fx4 acc = {0.f, 0.f, 0.f, 0.f};

    for (;;) {
        const int stop = min(s_ends[seg], rend);
        int cnt = (stop - r + 3) >> 2;    // this wave's rows in [r, stop)
        if (cnt < 0) cnt = 0;
        r += cnt << 2;

        int k = 0;
        for (; k + 4 <= cnt; k += 4) {    // 4 outstanding 16B loads/lane
            fx4 v0 = *(const fx4*)(p);
            fx4 v1 = *(const fx4*)(p + 4  * UNITS);
            fx4 v2 = *(const fx4*)(p + 8  * UNITS);
            fx4 v3 = *(const fx4*)(p + 12 * UNITS);
            p += 16 * UNITS;
            acc += (v0 + v1) + (v2 + v3);
        }
        for (; k < cnt; ++k) {
            fx4 v = *(const fx4*)(p);
            p += 4 * UNITS;
            acc += v;
        }

        // ---- flush: 4-wave LDS reduce, 1 atomic per thread ----
        *reinterpret_cast<fx4*>(&s_red[rl][ln][0]) = acc;
        __syncthreads();
        {
            const int q  = t >> 2, e = t & 3;
            const float vsum = s_red[0][q][e] + s_red[1][q][e]
                             + s_red[2][q][e] + s_red[3][q][e];
            unsafeAtomicAdd(out + seg * UNITS + t, vsum * s_inv[seg]);
        }
        if (s_ends[seg] >= rend) break;   // last intersecting segment: uniform
        ++seg;
        acc = fx4{0.f, 0.f, 0.f, 0.f};
        __syncthreads();                  // protect s_red reuse
    }
}

extern "C" void kernel_launch(void* const* d_in, const int* in_sizes, int n_in,
                              void* d_out, int out_size, void* d_ws, size_t ws_size,
                              hipStream_t stream) {
    const float* x        = (const float*)d_in[0];
    const int*   nclasses = (const int*)d_in[1];
    const int*   nfeature = (const int*)d_in[2];
    float*       out      = (float*)d_out;

    const int total_rows = in_sizes[0] / UNITS;

    // balanced two-tier chunking over exactly 2048 blocks
    const int q   = total_rows >> 11;         // total/2048
    const int lo  = q & ~3;                   // lower chunk, multiple of 4
    const int E   = total_rows - (lo << 11);  // leftover rows
    const int nE4 = (E + 3) >> 2;             // blocks that take lo+4 rows

    k_zero<<<64, 256, 0, stream>>>(out);
    k_accum<<<2048, 256, 0, stream>>>(x, nclasses, nfeature, out,
                                      total_rows, lo, nE4);
}